// Round 9
// baseline (204.510 us; speedup 1.0000x reference)
//
#include <hip/hip_runtime.h>
#include <stdint.h>

// ---------- types ----------
typedef __bf16 bf16x8 __attribute__((ext_vector_type(8)));
typedef float f32x4 __attribute__((ext_vector_type(4)));
typedef unsigned short u16x4 __attribute__((ext_vector_type(4)));

static __device__ __forceinline__ unsigned short f2bf(float f) {
    union { float f; unsigned u; } v; v.f = f;
    unsigned r = (v.u + 0x7FFFu + ((v.u >> 16) & 1u)) >> 16;  // RNE
    return (unsigned short)r;
}

// ---------- fused prep: convert X, convert adj, transpose W0/W1/W2 ----------
// XCD-affine element mapping (round 8): XCD x (= bid%8) converts the
// nodes/graphs its GEMM blocks will consume.
__global__ void prep_kernel(const float* __restrict__ X,
                            const float* __restrict__ adj,
                            const float* __restrict__ W0,
                            const float* __restrict__ W1,
                            const float* __restrict__ W2,
                            unsigned short* __restrict__ bufH,
                            unsigned short* __restrict__ adjB,
                            unsigned short* __restrict__ Wt) {
    const int bid = blockIdx.x;
    const int t = threadIdx.x;
    if (bid < 16384) {
        const float* src = (bid < 8192) ? X : adj;
        unsigned short* dst = (bid < 8192) ? bufH : adjB;
        const int q = bid & 8191;
        const int i = (q & 7) * 262144 + (q >> 3) * 256 + t;
        f32x4 v = ((const f32x4*)src)[i];
        u16x4 o;
        o.x = f2bf(v.x); o.y = f2bf(v.y); o.z = f2bf(v.z); o.w = f2bf(v.w);
        ((u16x4*)dst)[i] = o;
    } else {
        const int wb = bid - 16384;          // 0..767
        const int z = wb >> 8;               // which W
        const int tile = wb & 255;           // 16x16 tiles of 32x32
        const float* W = (z == 0) ? W0 : (z == 1) ? W1 : W2;
        unsigned short* out = Wt + (size_t)z * (512 * 512);
        __shared__ float tileS[32][33];
        const int bx = (tile & 15) * 32, by = (tile >> 4) * 32;
        const int tx = t & 31, ty = t >> 5;  // 32 x 8
        #pragma unroll
        for (int r = 0; r < 32; r += 8)
            tileS[ty + r][tx] = W[(size_t)(by + ty + r) * 512 + (bx + tx)];
        __syncthreads();
        #pragma unroll
        for (int r = 0; r < 32; r += 8)
            out[(size_t)(bx + ty + r) * 512 + (by + tx)] = f2bf(tileS[tx][ty + r]);
    }
}

// ---------- GEMM: D[m][n] = sum_k A[m*LDA+k]*B[n*LDB+k]; writes out[n*LDO+m]
// NEW this round: 128x256 tile (BM=128, BN=256), BK=64 double-buffered,
// 512 threads / 8 waves (wave grid 2m x 4n, wave-tile 64x64, acc[4][4] ->
// 32 MFMA per buffer-phase per wave). Staged bytes drop 31% vs 128^2
// (A staged N/256=2x instead of 4x). Grid = 256 blocks = 1 block/CU,
// LDS 96 KB (A dbuf 2x16KB + B dbuf 2x32KB).
// Counted-vmcnt pipeline: STAGE = 6 loads/thread (2 A rounds + 4 B rounds);
// steady-state wait vmcnt(6) (own buffer landed, next buffer in flight).
// LDS: 16B chunks, 8/row, linear dest + pre-swizzled global source column
// (rule #21); read idx = row*8 + (want ^ (row&7)).
// Epilogue: coalesced via LDS transpose; f32 in two 64KB halves.
template<int LDA, int LDB, int LDO, bool BIAS, bool RELU, bool ADJ, typename OT>
__global__ __launch_bounds__(512, 2)
void gemm_abT_ct(const unsigned short* __restrict__ A,
                 const unsigned short* __restrict__ B,
                 OT* __restrict__ out, const float* __restrict__ bias,
                 long batchA, long batchB, long batchO) {
    __shared__ char SMEM[98304];   // A: 2x16KB at 0; B: 2x32KB at 32768

    const int tid  = threadIdx.x;          // 0..511
    const int lane = tid & 63;
    const int wave = tid >> 6;             // 0..7
    const int quad = lane >> 4;
    const int l16  = lane & 15;
    const int wm   = wave & 1;             // m-half (64 rows of 128)
    const int wn   = wave >> 1;            // n-quarter (64 cols of 256)

    // ---- XCD decode (bijective over 256 blocks; hw round-robins bid%8;
    // node partition: XCD x owns nodes [2048x, 2048x+2048) == graphs [4x,4x+4)) ----
    const int L = blockIdx.x;
    const int x = L & 7;        // XCD id
    const int j = L >> 3;       // 0..31 within XCD
    int m0, n0;
    long z;
    if constexpr (ADJ) {
        z = 4 * x + (j >> 3);             // graphs [4x, 4x+4) on XCD x
        const int loc = j & 7;            // 4 m-tiles x 2 n-tiles of this z
        m0 = (loc & 3) * 128;
        n0 = (loc >> 2) * 256;
    } else {
        z = 0;
        m0 = (x * 16 + (j >> 1)) * 128;   // XCD x owns m-tiles [16x,16x+16)
        n0 = (j & 1) * 256;
    }
    A   += (size_t)z * batchA;
    B   += (size_t)z * batchB;
    out += (size_t)z * batchO;

    const int trow8 = tid >> 3;                   // 0..63
    const int tpos8 = (tid & 7) ^ (trow8 & 7);    // pre-swizzled source column
    const unsigned short* aG = A + (size_t)(m0 + trow8) * LDA + tpos8 * 8;
    const unsigned short* bG = B + (size_t)(n0 + trow8) * LDB + tpos8 * 8;

    f32x4 acc[4][4];
    #pragma unroll
    for (int i = 0; i < 4; ++i)
        #pragma unroll
        for (int j2 = 0; j2 < 4; ++j2) {
            f32x4 zz = {0.f, 0.f, 0.f, 0.f};
            acc[i][j2] = zz;
        }

// issue 6 global_load_lds (2 A rounds + 4 B rounds) into buffer `buf`
// dest is LINEAR (base + tid*16 + r*8192); source column pre-swizzled.
#define STAGE(buf, ko)                                                         \
    do {                                                                       \
        char* aL = SMEM + (buf) * 16384 + tid * 16;                            \
        char* bL = SMEM + 32768 + (buf) * 32768 + tid * 16;                    \
        _Pragma("unroll")                                                      \
        for (int r = 0; r < 2; ++r)                                            \
            __builtin_amdgcn_global_load_lds(                                  \
                (__attribute__((address_space(1))) void*)(uintptr_t)(aG + (size_t)(r * 64) * LDA + (ko)), \
                (__attribute__((address_space(3))) void*)(aL + r * 8192), 16, 0, 0); \
        _Pragma("unroll")                                                      \
        for (int r = 0; r < 4; ++r)                                            \
            __builtin_amdgcn_global_load_lds(                                  \
                (__attribute__((address_space(1))) void*)(uintptr_t)(bG + (size_t)(r * 64) * LDB + (ko)), \
                (__attribute__((address_space(3))) void*)(bL + r * 8192), 16, 0, 0); \
    } while (0)

// 2 ks-steps x (4+4 ds_read_b128 + 16 MFMA) on buffer `buf`
#define COMPUTE(buf)                                                           \
    do {                                                                       \
        const char* Ab = SMEM + (buf) * 16384;                                 \
        const char* Bb = SMEM + 32768 + (buf) * 32768;                         \
        _Pragma("unroll")                                                      \
        for (int ks = 0; ks < 2; ++ks) {                                       \
            bf16x8 af[4], bfr[4];                                              \
            _Pragma("unroll")                                                  \
            for (int i = 0; i < 4; ++i) {                                      \
                const int row = wm * 64 + i * 16 + l16;                        \
                const int idx = row * 8 + ((ks * 4 + quad) ^ (row & 7));       \
                af[i] = *(const bf16x8*)(Ab + idx * 16);                       \
            }                                                                  \
            _Pragma("unroll")                                                  \
            for (int j2 = 0; j2 < 4; ++j2) {                                   \
                const int row = wn * 64 + j2 * 16 + l16;                       \
                const int idx = row * 8 + ((ks * 4 + quad) ^ (row & 7));       \
                bfr[j2] = *(const bf16x8*)(Bb + idx * 16);                     \
            }                                                                  \
            _Pragma("unroll")                                                  \
            for (int i = 0; i < 4; ++i)                                        \
                _Pragma("unroll")                                              \
                for (int j2 = 0; j2 < 4; ++j2)                                 \
                    acc[i][j2] = __builtin_amdgcn_mfma_f32_16x16x32_bf16(af[i], bfr[j2], acc[i][j2], 0, 0, 0); \
        }                                                                      \
    } while (0)

    STAGE(0, 0);     // -> buf0
    STAGE(1, 64);    // -> buf1   (12 loads/thread in flight)

    #pragma unroll 1
    for (int kp = 0; kp < 4; ++kp) {       // K = 512 = 4 x (two 64-halves)
        const int ko = kp * 128;
        // ---- half A: buf0 (k = ko) ----
        asm volatile("s_waitcnt vmcnt(6)" ::: "memory");   // my buf0 loads done
        __builtin_amdgcn_s_barrier();                      // all waves ready
        __builtin_amdgcn_s_setprio(1);
        COMPUTE(0);
        __builtin_amdgcn_s_setprio(0);
        asm volatile("s_waitcnt lgkmcnt(0)" ::: "memory"); // my ds_reads done
        __builtin_amdgcn_sched_barrier(0);
        __builtin_amdgcn_s_barrier();                      // all waves done reading buf0
        if (kp < 3) STAGE(0, ko + 128);                    // refill buf0
        // ---- half B: buf1 (k = ko + 64) ----
        if (kp < 3) asm volatile("s_waitcnt vmcnt(6)" ::: "memory");
        else        asm volatile("s_waitcnt vmcnt(0)" ::: "memory");
        __builtin_amdgcn_s_barrier();
        __builtin_amdgcn_s_setprio(1);
        COMPUTE(1);
        __builtin_amdgcn_s_setprio(0);
        asm volatile("s_waitcnt lgkmcnt(0)" ::: "memory");
        __builtin_amdgcn_sched_barrier(0);
        __builtin_amdgcn_s_barrier();
        if (kp < 3) STAGE(1, ko + 192);
    }
#undef STAGE
#undef COMPUTE

    // ---- coalesced epilogue via LDS transpose (K-loop ended with full
    // drain + barrier -> SMEM reusable). Tile is m=128 x n=256. ----
    if constexpr (sizeof(OT) == 2) {
        // bf16 T[n=256][m=128]: 256 rows x 256B (16 chunks), chunk ^= n&7 -> 64 KB
        unsigned short* T = (unsigned short*)SMEM;
        #pragma unroll
        for (int i = 0; i < 4; ++i) {
            const int mloc = wm * 64 + i * 16 + quad * 4;
            const int mb = m0 + mloc;
            f32x4 bb = {0.f, 0.f, 0.f, 0.f};
            if constexpr (BIAS) bb = *(const f32x4*)(bias + mb);
            const int ch  = mloc >> 3;           // 16B chunk 0..15
            const int sub = (mloc & 7) * 2;      // byte offset in chunk (0/8)
            #pragma unroll
            for (int j2 = 0; j2 < 4; ++j2) {
                const int nloc = wn * 64 + j2 * 16 + l16;   // 0..255
                f32x4 v = acc[i][j2];
                if constexpr (BIAS) v += bb;
                if constexpr (RELU) {
                    v.x = v.x > 0.f ? v.x : 0.f;
                    v.y = v.y > 0.f ? v.y : 0.f;
                    v.z = v.z > 0.f ? v.z : 0.f;
                    v.w = v.w > 0.f ? v.w : 0.f;
                }
                u16x4 o;
                o.x = f2bf(v.x); o.y = f2bf(v.y); o.z = f2bf(v.z); o.w = f2bf(v.w);
                *(u16x4*)((char*)T + nloc * 256 + ((ch ^ (nloc & 7)) << 4) + sub) = o;
            }
        }
        __syncthreads();
        #pragma unroll
        for (int it = 0; it < 8; ++it) {
            const int n  = (tid >> 4) + 32 * it;   // 0..255
            const int cc = tid & 15;               // 16 lanes = 256B dense row
            f32x4 d = *(const f32x4*)((const char*)T + n * 256 + ((cc ^ (n & 7)) << 4));
            *(f32x4*)((unsigned short*)out + (size_t)(n0 + n) * LDO + m0 + cc * 8) = d;
        }
    } else {
        // f32 T[n=128][m=128] per half: 128 rows x 512B (32 chunks) = 64 KB; 2 halves
        float* T = (float*)SMEM;
        #pragma unroll
        for (int h = 0; h < 2; ++h) {
            if ((wn >> 1) == h) {
                #pragma unroll
                for (int i = 0; i < 4; ++i) {
                    const int mloc = wm * 64 + i * 16 + quad * 4;
                    const int mb = m0 + mloc;
                    f32x4 bb = {0.f, 0.f, 0.f, 0.f};
                    if constexpr (BIAS) bb = *(const f32x4*)(bias + mb);
                    const int ch = mloc >> 2;            // 16B chunk 0..31
                    #pragma unroll
                    for (int j2 = 0; j2 < 4; ++j2) {
                        const int nl = wn * 64 + j2 * 16 + l16 - h * 128;  // 0..127
                        f32x4 v = acc[i][j2];
                        if constexpr (BIAS) v += bb;
                        if constexpr (RELU) {
                            v.x = v.x > 0.f ? v.x : 0.f;
                            v.y = v.y > 0.f ? v.y : 0.f;
                            v.z = v.z > 0.f ? v.z : 0.f;
                            v.w = v.w > 0.f ? v.w : 0.f;
                        }
                        *(f32x4*)((char*)T + nl * 512 + ((ch ^ (nl & 7)) << 4)) = v;
                    }
                }
            }
            __syncthreads();
            #pragma unroll
            for (int it = 0; it < 8; ++it) {
                const int nl = (tid >> 5) + 16 * it;   // 0..127
                const int cc = tid & 31;               // 32 lanes = 512B dense row
                f32x4 d = *(const f32x4*)((const char*)T + nl * 512 + ((cc ^ (nl & 7)) << 4));
                *(f32x4*)((float*)out + (size_t)(n0 + h * 128 + nl) * LDO + m0 + cc * 4) = d;
            }
            if (h == 0) __syncthreads();   // protect T reuse for half 1
        }
    }
}

extern "C" void kernel_launch(void* const* d_in, const int* in_sizes, int n_in,
                              void* d_out, int out_size, void* d_ws, size_t ws_size,
                              hipStream_t stream) {
    (void)in_sizes; (void)n_in; (void)out_size; (void)ws_size;
    const float* X   = (const float*)d_in[0];
    const float* adj = (const float*)d_in[1];
    const float* W0  = (const float*)d_in[2];
    const float* b0  = (const float*)d_in[3];
    const float* W1  = (const float*)d_in[4];
    const float* b1  = (const float*)d_in[5];
    const float* W2  = (const float*)d_in[6];
    const float* b2  = (const float*)d_in[7];
    float* out = (float*)d_out;

    // workspace layout (bf16): adjB | bufH (X/h, node-major) | tmpT (feat-major) | Wt x3
    char* ws = (char*)d_ws;
    const size_t SZ = 16777216;  // 32*512*512*2
    unsigned short* adjB = (unsigned short*)(ws);
    unsigned short* bufH = (unsigned short*)(ws + SZ);
    unsigned short* tmpT = (unsigned short*)(ws + 2 * SZ);
    unsigned short* Wt   = (unsigned short*)(ws + 3 * SZ);
    const unsigned short* W0t = Wt;
    const unsigned short* W1t = Wt + 262144;
    const unsigned short* W2t = Wt + 2 * 262144;

    prep_kernel<<<16384 + 768, 256, 0, stream>>>(X, adj, W0, W1, W2, bufH, adjB, Wt);

    const long BATCH = 512L * 512L;

    // layer 0: tmpT[e][node] = (h @ W0);  h = relu(adj @ tmp + b0) node-major
    gemm_abT_ct<512, 512, 16384, false, false, false, unsigned short>
        <<<256, 512, 0, stream>>>(bufH, W0t, tmpT, nullptr, 0, 0, 0);
    gemm_abT_ct<16384, 512, 512, true, true, true, unsigned short>
        <<<256, 512, 0, stream>>>(tmpT, adjB, bufH, b0, 512, BATCH, BATCH);
    // layer 1
    gemm_abT_ct<512, 512, 16384, false, false, false, unsigned short>
        <<<256, 512, 0, stream>>>(bufH, W1t, tmpT, nullptr, 0, 0, 0);
    gemm_abT_ct<16384, 512, 512, true, true, true, unsigned short>
        <<<256, 512, 0, stream>>>(tmpT, adjB, bufH, b1, 512, BATCH, BATCH);
    // layer 2 (no relu, fp32 out)
    gemm_abT_ct<512, 512, 16384, false, false, false, unsigned short>
        <<<256, 512, 0, stream>>>(bufH, W2t, tmpT, nullptr, 0, 0, 0);
    gemm_abT_ct<16384, 512, 512, true, false, true, float>
        <<<256, 512, 0, stream>>>(tmpT, adjB, out, b2, 512, BATCH, BATCH);
}